// Round 10
// baseline (2844.122 us; speedup 1.0000x reference)
//
#include <hip/hip_runtime.h>
#include <hip/hip_bf16.h>
#include <hip/hip_fp16.h>

typedef _Float16 f16;
typedef __hip_bfloat16 bf16;
typedef short bf16x8 __attribute__((ext_vector_type(8)));
typedef float f32x4 __attribute__((ext_vector_type(4)));
typedef int i32x4 __attribute__((ext_vector_type(4)));
typedef _Float16 f16x2 __attribute__((ext_vector_type(2)));

#define HDIM 256
#define G4   1024
#define TT   2048
#define NB   64
#define NTOK (64*2048)
#define MPAD 384   // 341 padded to 384 (6 x 64)

// ---------------- helpers ----------------
__device__ __forceinline__ int dot4i(unsigned a, unsigned b, int c) {
#if __has_builtin(__builtin_amdgcn_sdot4)
    return __builtin_amdgcn_sdot4((int)a, (int)b, c, false);
#else
    char4 x = __builtin_bit_cast(char4, a), y = __builtin_bit_cast(char4, b);
    return c + (int)x.x*(int)y.x + (int)x.y*(int)y.y + (int)x.z*(int)y.z + (int)x.w*(int)y.w;
#endif
}

// reduce across the 4 lanes of a quad (lane bits 0..1) on the VALU pipe.
__device__ __forceinline__ int quad_red(int v) {
#if __has_builtin(__builtin_amdgcn_update_dpp)
    v += __builtin_amdgcn_update_dpp(0, v, 0xB1, 0xF, 0xF, true);
    v += __builtin_amdgcn_update_dpp(0, v, 0x4E, 0xF, 0xF, true);
    return v;
#else
    v += __shfl_xor(v, 1, 64);
    v += __shfl_xor(v, 2, 64);
    return v;
#endif
}

__device__ __forceinline__ float gelu_tanh(float x) {
    // jax.nn.gelu default (approximate=True)
    float x3 = x*x*x;
    float t = tanhf(0.7978845608028654f * (x + 0.044715f * x3));
    return 0.5f * x * (1.0f + t);
}

// ---------------- prep: dtype conversion + padding ----------------
__global__ void k_prep_w(const float* __restrict__ W, bf16* __restrict__ Wb) {
    int i = blockIdx.x*256 + threadIdx.x;          // 262144 total
    Wb[i] = __float2bfloat16(W[i]);
}

// R -> int8 with per-gate-row scale. One wave per row (256 f32 -> 256 i8).
__global__ __launch_bounds__(256) void k_prep_r8(const float* __restrict__ R,
        char* __restrict__ R8, float* __restrict__ rscale) {
    int wave = threadIdx.x >> 6, lane = threadIdx.x & 63;
    int g = blockIdx.x*4 + wave;
    float4 v = ((const float4*)(R + (long)g*256))[lane];
    float mx = fmaxf(fmaxf(fabsf(v.x), fabsf(v.y)), fmaxf(fabsf(v.z), fabsf(v.w)));
    #pragma unroll
    for (int m = 1; m < 64; m <<= 1) mx = fmaxf(mx, __shfl_xor(mx, m, 64));
    float inv = (mx > 0.f) ? 127.f/mx : 0.f;
    int q0 = (int)rintf(v.x*inv), q1 = (int)rintf(v.y*inv);
    int q2 = (int)rintf(v.z*inv), q3 = (int)rintf(v.w*inv);
    unsigned packed = (q0 & 0xff) | ((q1 & 0xff) << 8) | ((q2 & 0xff) << 16) | ((q3 & 0xff) << 24);
    ((unsigned*)(R8 + (long)g*256))[lane] = packed;
    if (lane == 0) rscale[g] = mx * (1.0f/127.f);
}

__global__ void k_prep_gu(const float* __restrict__ gW, const float* __restrict__ uW,
                          const float* __restrict__ gb, const float* __restrict__ ub,
                          bf16* __restrict__ gWb, bf16* __restrict__ uWb,
                          float* __restrict__ gbp, float* __restrict__ ubp) {
    int i = blockIdx.x*256 + threadIdx.x;          // 384*256 total
    int r = i >> 8, c = i & 255;
    gWb[i] = __float2bfloat16(r < 341 ? gW[r*256 + c] : 0.f);
    uWb[i] = __float2bfloat16(r < 341 ? uW[r*256 + c] : 0.f);
    if (i < 384) {
        gbp[i] = i < 341 ? gb[i] : 0.f;
        ubp[i] = i < 341 ? ub[i] : 0.f;
    }
}

__global__ void k_prep_down(const float* __restrict__ dW, bf16* __restrict__ dWb) {
    int i = blockIdx.x*256 + threadIdx.x;          // 256*384 total
    int r = i / 384, c = i % 384;
    dWb[i] = __float2bfloat16(c < 341 ? dW[r*341 + c] : 0.f);
}

// ---------------- LayerNorm 1: f32 -> bf16 ----------------
__global__ __launch_bounds__(256) void k_ln1(const float* __restrict__ x,
        const float* __restrict__ w, const float* __restrict__ b,
        bf16* __restrict__ nx) {
    int wave = threadIdx.x >> 6, lane = threadIdx.x & 63;
    long tok = (long)blockIdx.x * 4 + wave;
    float4 v = ((const float4*)(x + tok*HDIM))[lane];
    float s = v.x + v.y + v.z + v.w;
    float q = v.x*v.x + v.y*v.y + v.z*v.z + v.w*v.w;
    #pragma unroll
    for (int m = 1; m < 64; m <<= 1) { s += __shfl_xor(s, m, 64); q += __shfl_xor(q, m, 64); }
    float mean = s * (1.0f/HDIM);
    float rs = rsqrtf(q*(1.0f/HDIM) - mean*mean + 1e-5f);
    float4 wv = ((const float4*)w)[lane];
    float4 bv = ((const float4*)b)[lane];
    bf16 tmp[4];
    tmp[0] = __float2bfloat16((v.x-mean)*rs*wv.x + bv.x);
    tmp[1] = __float2bfloat16((v.y-mean)*rs*wv.y + bv.y);
    tmp[2] = __float2bfloat16((v.z-mean)*rs*wv.z + bv.z);
    tmp[3] = __float2bfloat16((v.w-mean)*rs*wv.w + bv.w);
    *(ushort4*)(nx + tok*HDIM + lane*4) = *(ushort4*)tmp;
}

// ---------------- LayerNorm 2 + residual: f16 mlp + f32 x -> f32 out ----------------
__global__ __launch_bounds__(256) void k_ln2(const f16* __restrict__ mlp,
        const float* __restrict__ x, const float* __restrict__ w,
        const float* __restrict__ b, float* __restrict__ out) {
    int wave = threadIdx.x >> 6, lane = threadIdx.x & 63;
    long tok = (long)blockIdx.x * 4 + wave;
    const f16* mr = mlp + tok*HDIM + lane*4;
    float4 v; v.x = (float)mr[0]; v.y = (float)mr[1]; v.z = (float)mr[2]; v.w = (float)mr[3];
    float s = v.x + v.y + v.z + v.w;
    float q = v.x*v.x + v.y*v.y + v.z*v.z + v.w*v.w;
    #pragma unroll
    for (int m = 1; m < 64; m <<= 1) { s += __shfl_xor(s, m, 64); q += __shfl_xor(q, m, 64); }
    float mean = s * (1.0f/HDIM);
    float rs = rsqrtf(q*(1.0f/HDIM) - mean*mean + 1e-5f);
    float4 wv = ((const float4*)w)[lane];
    float4 bv = ((const float4*)b)[lane];
    float4 xv = ((const float4*)(x + tok*HDIM))[lane];
    float4 ov;
    ov.x = (v.x-mean)*rs*wv.x + bv.x + xv.x;
    ov.y = (v.y-mean)*rs*wv.y + bv.y + xv.y;
    ov.z = (v.z-mean)*rs*wv.z + bv.z + xv.z;
    ov.w = (v.w-mean)*rs*wv.w + bv.w + xv.w;
    ((float4*)(out + tok*HDIM))[lane] = ov;
}

// ---------------- GEMM: C[M x N] = A[M x K] * B[N x K]^T + bias ----------------
// MODE_XW_F16 writes gate-interleaved layout: [m][n&255][n>>8] (4 f16 per row j).
enum { MODE_F16 = 0, MODE_GELU_F16 = 1, MODE_MUL_BF16 = 2, MODE_XW_F16 = 3 };

template<int MODE>
__global__ __launch_bounds__(256) void k_gemm(
    const bf16* __restrict__ A, const bf16* __restrict__ Bm,
    const float* __restrict__ bias, void* __restrict__ Cv,
    const f16* __restrict__ gatebuf,
    int K, int lda, int ldb, int ldc, int ldg)
{
    // BM=128, BN=64, BK=64; rows stored as 64 bf16 = 128B = 8x16B slots, XOR-swizzled
    __shared__ char Al[128*128];
    __shared__ char Bl[64*128];
    const int tid = threadIdx.x;
    const long bm = (long)blockIdx.x * 128;
    const int bn = blockIdx.y * 64;
    const int wave = tid >> 6, lane = tid & 63;
    const int wm = wave >> 1, wn = wave & 1;        // 2x2 waves, each 64x32
    const int l16 = lane & 15, lq = lane >> 4;
    f32x4 acc[4][2] = {};
    for (int k0 = 0; k0 < K; k0 += 64) {
        #pragma unroll
        for (int p = 0; p < 4; ++p) {               // A: 128 rows x 8 chunks
            int ci = tid + p*256;
            int row = ci >> 3, s = ci & 7;
            uint4 d = *(const uint4*)(A + (bm + row)*lda + k0 + s*8);
            *(uint4*)(Al + row*128 + ((s ^ (row&7))<<4)) = d;
        }
        #pragma unroll
        for (int p = 0; p < 2; ++p) {               // B: 64 rows x 8 chunks
            int ci = tid + p*256;
            int row = ci >> 3, s = ci & 7;
            uint4 d = *(const uint4*)(Bm + (long)(bn + row)*ldb + k0 + s*8);
            *(uint4*)(Bl + row*128 + ((s ^ (row&7))<<4)) = d;
        }
        __syncthreads();
        #pragma unroll
        for (int kc = 0; kc < 2; ++kc) {
            bf16x8 bf[2];
            #pragma unroll
            for (int fn = 0; fn < 2; ++fn) {
                int row = wn*32 + fn*16 + l16;
                int slot = (kc<<2) + lq;
                bf[fn] = *(const bf16x8*)(Bl + row*128 + ((slot ^ (row&7))<<4));
            }
            #pragma unroll
            for (int fm = 0; fm < 4; ++fm) {
                int row = wm*64 + fm*16 + l16;
                int slot = (kc<<2) + lq;
                bf16x8 af = *(const bf16x8*)(Al + row*128 + ((slot ^ (row&7))<<4));
                acc[fm][0] = __builtin_amdgcn_mfma_f32_16x16x32_bf16(af, bf[0], acc[fm][0], 0,0,0);
                acc[fm][1] = __builtin_amdgcn_mfma_f32_16x16x32_bf16(af, bf[1], acc[fm][1], 0,0,0);
            }
        }
        __syncthreads();
    }
    #pragma unroll
    for (int fm = 0; fm < 4; ++fm) {
        #pragma unroll
        for (int fn = 0; fn < 2; ++fn) {
            int n = bn + wn*32 + fn*16 + l16;
            float bv = bias[n];
            #pragma unroll
            for (int r = 0; r < 4; ++r) {
                long m = bm + wm*64 + fm*16 + lq*4 + r;
                float v = acc[fm][fn][r] + bv;
                if constexpr (MODE == MODE_F16) {
                    ((f16*)Cv)[m*ldc + n] = (f16)v;
                } else if constexpr (MODE == MODE_XW_F16) {
                    ((f16*)Cv)[m*ldc + ((n & 255) << 2) + (n >> 8)] = (f16)v;
                } else if constexpr (MODE == MODE_GELU_F16) {
                    ((f16*)Cv)[m*ldc + n] = (f16)gelu_tanh(v);
                } else {
                    float g = (float)gatebuf[m*ldg + n];
                    ((bf16*)Cv)[m*ldc + n] = __float2bfloat16(g * v);
                }
            }
        }
    }
}

// ---------------- sLSTM scan: 64 blocks (1 batch each), 1024 threads / 16 waves ----
// ROLE SPLIT (this round): the scan is MFMA-issue-bound (i8 16x16x64 ~20 cyc/SIMD;
// 64 mfma/SIMD/step = 1306 cyc floor in R9). Split the GEMV across pipes:
//   waves 0-7  (MFMA role): j in [0,128). R9 structure: 16 mfma/wave/step
//       -> 128 mfma/CU/step = 653 cyc/SIMD on the matrix pipe.
//   waves 8-15 (VALU role): j in [128,256). R7 structure: kg=lane&3 k-slice,
//       64 dot4/lane + quad-DPP reduce -> ~500 cyc/SIMD on the VALU pipe.
// Both roles compute all 4 gates for their j's -> self-contained epilogues, one
// shared h ping-pong + raw s_barrier(lgkmcnt-only) per step. Integer math is
// identical in both paths (exact i8 dots). Separate loops per role so register
// allocation is independent (mfma Bf may live in AGPRs; dot4 needs VGPRs).
// s_setprio(1) wraps the mfma cluster (T5: role-split = the regime where it pays).

#define SLSTM_EPI_PUB(S0v, S1v, S2v, S3v, XREG)                                 \
        float pz = rs[0]*(float)(S0v) + (float)__builtin_bit_cast(f16x2, XREG.x)[0]; \
        float pi = rs[1]*(float)(S1v) + (float)__builtin_bit_cast(f16x2, XREG.x)[1]; \
        float pf = rs[2]*(float)(S2v) + (float)__builtin_bit_cast(f16x2, XREG.y)[0]; \
        float po = rs[3]*(float)(S3v) + (float)__builtin_bit_cast(f16x2, XREG.y)[1]; \
        float e = __expf(-2.0f * fabsf(pz));                                    \
        float z = copysignf((1.0f - e) / (1.0f + e), pz);                       \
        float o = 1.0f / (1.0f + __expf(-po));                                  \
        float mn = fmaxf(pf + mst, pi);                                         \
        float ig = __expf(pi - mn);                                             \
        float fg = __expf(pf + mst - mn);                                       \
        cst = fg*cst + ig*z;                                                    \
        nst = fg*nst + ig;                                                      \
        mst = mn;                                                               \
        float h = o * (cst / nst);                                              \
        if (pub) {                                                              \
            hq[cur^1][j] = (char)(int)rintf(h * 127.f);                         \
            hrow[j] = __float2bfloat16(h);                                      \
        }                                                                       \
        __builtin_amdgcn_sched_barrier(0);                                      \
        asm volatile("s_waitcnt lgkmcnt(0)" ::: "memory");                      \
        __builtin_amdgcn_s_barrier();                                           \
        __builtin_amdgcn_sched_barrier(0);                                      \
        cur ^= 1;                                                               \
        hrow += HDIM;

__global__ __launch_bounds__(1024) __attribute__((amdgpu_waves_per_eu(4, 4)))
void k_scan(const f16* __restrict__ xW, const char* __restrict__ R8,
            const float* __restrict__ rscale, bf16* __restrict__ h_out)
{
    __shared__ char hq[2][256];                      // i8 h, ping-pong
    const int tid = threadIdx.x;
    const int b    = blockIdx.x;
    const int w    = tid >> 6;                       // wave 0..15
    const int lane = tid & 63;

    if (tid < 64) ((unsigned*)hq[0])[tid] = 0u;
    __syncthreads();

    const char* xg0 = (const char*)xW + (long)b * TT * 2048;
    bf16* hrow = h_out + (long)b * TT * HDIM;

    if (w < 8) {
        // ================= MFMA role: j in [0,128) =================
        const int c = lane & 15;                     // j-column / gate-column
        const int q = lane >> 4;                     // k lane-group (0..3)
        const int j = w*16 + c;
        const bool pub = (q == 0);

        uint4 Bf[4][4];                              // Bf[m][kk] (AGPR-friendly)
        #pragma unroll
        for (int m = 0; m < 4; ++m)
            #pragma unroll
            for (int kk = 0; kk < 4; ++kk)
                Bf[m][kk] = *(const uint4*)(R8 + (long)(j + 256*m)*256 + kk*64 + q*16);
        float rs[4];
        #pragma unroll
        for (int m = 0; m < 4; ++m)
            rs[m] = rscale[j + 256*m] * (1.0f/127.0f);

        const char* xg = xg0 + j*8;
        uint2 XA = *(const uint2*)(xg);
        uint2 XB = *(const uint2*)(xg + 2048);
        float cst = 0.f, nst = 0.f, mst = 0.f;
        int cur = 0;

#define STEP_MFMA(XREG, TPRE)                                                   \
    do {                                                                        \
        uint2 Xc = XREG;                                                        \
        XREG = *(const uint2*)(xg + (long)(TPRE)*2048);                         \
        i32x4 af[4];                                                            \
        _Pragma("unroll")                                                       \
        for (int kk = 0; kk < 4; ++kk)                                          \
            af[kk] = __builtin_bit_cast(i32x4,                                  \
                         *(const uint4*)(hq[cur] + kk*64 + q*16));              \
        i32x4 ac0 = {0,0,0,0}, ac1 = {0,0,0,0}, ac2 = {0,0,0,0}, ac3 = {0,0,0,0}; \
        __builtin_amdgcn_s_setprio(1);                                          \
        _Pragma("unroll")                                                       \
        for (int kk = 0; kk < 4; ++kk) {                                        \
            ac0 = __builtin_amdgcn_mfma_i32_16x16x64_i8(af[kk], __builtin_bit_cast(i32x4, Bf[0][kk]), ac0, 0,0,0); \
            ac1 = __builtin_amdgcn_mfma_i32_16x16x64_i8(af[kk], __builtin_bit_cast(i32x4, Bf[1][kk]), ac1, 0,0,0); \
            ac2 = __builtin_amdgcn_mfma_i32_16x16x64_i8(af[kk], __builtin_bit_cast(i32x4, Bf[2][kk]), ac2, 0,0,0); \
            ac3 = __builtin_amdgcn_mfma_i32_16x16x64_i8(af[kk], __builtin_bit_cast(i32x4, Bf[3][kk]), ac3, 0,0,0); \
        }                                                                       \
        __builtin_amdgcn_s_setprio(0);                                          \
        SLSTM_EPI_PUB(ac0[0], ac1[0], ac2[0], ac3[0], Xc)                       \
    } while (0)

        for (int t = 0; t < TT; t += 2) {
            STEP_MFMA(XA, t + 2);
            STEP_MFMA(XB, t + 3);
        }
#undef STEP_MFMA
    } else {
        // ================= VALU role: j in [128,256) =================
        const int kg = lane & 3;                     // k-slice [kg*64, kg*64+64)
        const int jj = lane >> 2;                    // 0..15
        const int j = 128 + (w - 8)*16 + jj;
        const bool pub = (kg == 0);

        uint4 Rq[4][4];                              // Rq[m][i] (must stay VGPR)
        #pragma unroll
        for (int m = 0; m < 4; ++m)
            #pragma unroll
            for (int i = 0; i < 4; ++i)
                Rq[m][i] = *(const uint4*)(R8 + (long)(j + 256*m)*256 + kg*64 + i*16);
        float rs[4];
        #pragma unroll
        for (int m = 0; m < 4; ++m)
            rs[m] = rscale[j + 256*m] * (1.0f/127.0f);

        const char* xg = xg0 + j*8;
        uint2 XA = *(const uint2*)(xg);
        uint2 XB = *(const uint2*)(xg + 2048);
        float cst = 0.f, nst = 0.f, mst = 0.f;
        int cur = 0;

#define STEP_VALU(XREG, TPRE)                                                   \
    do {                                                                        \
        uint2 Xc = XREG;                                                        \
        XREG = *(const uint2*)(xg + (long)(TPRE)*2048);                         \
        int S0 = 0, S1 = 0, S2 = 0, S3 = 0;                                     \
        _Pragma("unroll")                                                       \
        for (int i = 0; i < 4; ++i) {                                           \
            uint4 hv = *(const uint4*)(hq[cur] + kg*64 + i*16);                 \
            uint4 r0 = Rq[0][i], r1 = Rq[1][i], r2 = Rq[2][i], r3 = Rq[3][i];   \
            S0 = dot4i(r0.x, hv.x, S0); S0 = dot4i(r0.y, hv.y, S0);             \
            S0 = dot4i(r0.z, hv.z, S0); S0 = dot4i(r0.w, hv.w, S0);             \
            S1 = dot4i(r1.x, hv.x, S1); S1 = dot4i(r1.y, hv.y, S1);             \
            S1 = dot4i(r1.z, hv.z, S1); S1 = dot4i(r1.w, hv.w, S1);             \
            S2 = dot4i(r2.x, hv.x, S2); S2 = dot4i(r2.y, hv.y, S2);             \
            S2 = dot4i(r2.z, hv.z, S2); S2 = dot4i(r2.w, hv.w, S2);             \
            S3 = dot4i(r3.x, hv.x, S3); S3 = dot4i(r3.y, hv.y, S3);             \
            S3 = dot4i(r3.z, hv.z, S3); S3 = dot4i(r3.w, hv.w, S3);             \
        }                                                                       \
        S0 = quad_red(S0); S1 = quad_red(S1);                                   \
        S2 = quad_red(S2); S3 = quad_red(S3);                                   \
        SLSTM_EPI_PUB(S0, S1, S2, S3, Xc)                                       \
    } while (0)

        for (int t = 0; t < TT; t += 2) {
            STEP_VALU(XA, t + 2);
            STEP_VALU(XB, t + 3);
        }
#undef STEP_VALU
    }
}

// ---------------- launch ----------------
extern "C" void kernel_launch(void* const* d_in, const int* in_sizes, int n_in,
                              void* d_out, int out_size, void* d_ws, size_t ws_size,
                              hipStream_t stream) {
    const float* x     = (const float*)d_in[0];
    const float* ln1w  = (const float*)d_in[1];
    const float* ln1b  = (const float*)d_in[2];
    const float* W     = (const float*)d_in[3];
    const float* R     = (const float*)d_in[4];
    const float* bg    = (const float*)d_in[5];
    const float* upW   = (const float*)d_in[6];
    const float* upb   = (const float*)d_in[7];
    const float* gateW = (const float*)d_in[8];
    const float* gateb = (const float*)d_in[9];
    const float* downW = (const float*)d_in[10];
    const float* downb = (const float*)d_in[11];
    const float* ln2w  = (const float*)d_in[12];
    const float* ln2b  = (const float*)d_in[13];

    char* ws = (char*)d_ws;
    size_t off = 0;
    auto alloc = [&](size_t bytes) { char* p = ws + off; off += (bytes + 255) & ~255ULL; return p; };
    f16*  mlp16   = (f16*)alloc((size_t)NTOK*HDIM*2);     // holds nx first, then mlp (disjoint lifetimes)
    char* regionB = alloc((size_t)NTOK*G4*2);             // xW, then gate_out+prod
    bf16* h       = (bf16*)alloc((size_t)NTOK*HDIM*2);
    bf16* Wb      = (bf16*)alloc(262144*2);
    char* R8      = (char*)alloc(262144);
    float* rscale = (float*)alloc(1024*4);
    bf16* gWb     = (bf16*)alloc((size_t)MPAD*256*2);
    bf16* uWb     = (bf16*)alloc((size_t)MPAD*256*2);
    bf16* dWb     = (bf16*)alloc((size_t)256*MPAD*2);
    float* gbp    = (float*)alloc(MPAD*4);
    float* ubp    = (float*)alloc(MPAD*4);

    bf16* nx       = (bf16*)mlp16;                        // phase 1 use of that region
    f16*  xWb      = (f16*)regionB;                       // 131072 x 1024 f16 (gate-interleaved)
    f16*  gate_out = (f16*)regionB;                       // reuse after scan: 131072 x 384 f16
    bf16* prod     = (bf16*)(regionB + (size_t)NTOK*MPAD*2);

    k_prep_w   <<<1024, 256, 0, stream>>>(W, Wb);
    k_prep_r8  <<<256, 256, 0, stream>>>(R, R8, rscale);
    k_prep_gu  <<<384, 256, 0, stream>>>(gateW, upW, gateb, upb, gWb, uWb, gbp, ubp);
    k_prep_down<<<384, 256, 0, stream>>>(downW, dWb);
    k_ln1      <<<NTOK/4, 256, 0, stream>>>(x, ln1w, ln1b, nx);
    // xW = nx @ W^T + b   (f16, gate-interleaved per token)
    k_gemm<MODE_XW_F16><<<dim3(1024, 16), 256, 0, stream>>>(nx, Wb, bg, xWb, nullptr, 256, 256, 256, 1024, 0);
    // sequential sLSTM scan (MFMA + VALU role split)
    k_scan     <<<64, 1024, 0, stream>>>(xWb, R8, rscale, h);
    // gate = gelu(h @ gateW^T + gate_b)  (f16)
    k_gemm<MODE_GELU_F16><<<dim3(1024, 6), 256, 0, stream>>>(h, gWb, gbp, gate_out, nullptr, 256, 256, 256, MPAD, 0);
    // prod = gate * (h @ upW^T + up_b)   (bf16, padded cols auto-zero)
    k_gemm<MODE_MUL_BF16><<<dim3(1024, 6), 256, 0, stream>>>(h, uWb, ubp, prod, gate_out, 256, 256, 256, MPAD, MPAD);
    // mlp = prod @ downW^T + down_b      (f16 out, K=384)
    k_gemm<MODE_F16><<<dim3(1024, 4), 256, 0, stream>>>(prod, dWb, downb, mlp16, nullptr, MPAD, MPAD, MPAD, HDIM, 0);
    // out = LN(mlp) + x
    k_ln2      <<<NTOK/4, 256, 0, stream>>>(mlp16, x, ln2w, ln2b, (float*)d_out);
}

// Round 11
// 2616.099 us; speedup vs baseline: 1.0872x; 1.0872x over previous
//
#include <hip/hip_runtime.h>
#include <hip/hip_bf16.h>
#include <hip/hip_fp16.h>

typedef _Float16 f16;
typedef __hip_bfloat16 bf16;
typedef short bf16x8 __attribute__((ext_vector_type(8)));
typedef float f32x4 __attribute__((ext_vector_type(4)));
typedef int i32x4 __attribute__((ext_vector_type(4)));
typedef _Float16 f16x2 __attribute__((ext_vector_type(2)));

#define HDIM 256
#define G4   1024
#define TT   2048
#define NB   64
#define NTOK (64*2048)
#define MPAD 384   // 341 padded to 384 (6 x 64)

// ---------------- helpers ----------------
__device__ __forceinline__ float gelu_tanh(float x) {
    // jax.nn.gelu default (approximate=True)
    float x3 = x*x*x;
    float t = tanhf(0.7978845608028654f * (x + 0.044715f * x3));
    return 0.5f * x * (1.0f + t);
}

// ---------------- prep: dtype conversion + padding ----------------
__global__ void k_prep_w(const float* __restrict__ W, bf16* __restrict__ Wb) {
    int i = blockIdx.x*256 + threadIdx.x;          // 262144 total
    Wb[i] = __float2bfloat16(W[i]);
}

// R -> int8 with per-gate-row scale. One wave per row (256 f32 -> 256 i8).
__global__ __launch_bounds__(256) void k_prep_r8(const float* __restrict__ R,
        char* __restrict__ R8, float* __restrict__ rscale) {
    int wave = threadIdx.x >> 6, lane = threadIdx.x & 63;
    int g = blockIdx.x*4 + wave;
    float4 v = ((const float4*)(R + (long)g*256))[lane];
    float mx = fmaxf(fmaxf(fabsf(v.x), fabsf(v.y)), fmaxf(fabsf(v.z), fabsf(v.w)));
    #pragma unroll
    for (int m = 1; m < 64; m <<= 1) mx = fmaxf(mx, __shfl_xor(mx, m, 64));
    float inv = (mx > 0.f) ? 127.f/mx : 0.f;
    int q0 = (int)rintf(v.x*inv), q1 = (int)rintf(v.y*inv);
    int q2 = (int)rintf(v.z*inv), q3 = (int)rintf(v.w*inv);
    unsigned packed = (q0 & 0xff) | ((q1 & 0xff) << 8) | ((q2 & 0xff) << 16) | ((q3 & 0xff) << 24);
    ((unsigned*)(R8 + (long)g*256))[lane] = packed;
    if (lane == 0) rscale[g] = mx * (1.0f/127.f);
}

__global__ void k_prep_gu(const float* __restrict__ gW, const float* __restrict__ uW,
                          const float* __restrict__ gb, const float* __restrict__ ub,
                          bf16* __restrict__ gWb, bf16* __restrict__ uWb,
                          float* __restrict__ gbp, float* __restrict__ ubp) {
    int i = blockIdx.x*256 + threadIdx.x;          // 384*256 total
    int r = i >> 8, c = i & 255;
    gWb[i] = __float2bfloat16(r < 341 ? gW[r*256 + c] : 0.f);
    uWb[i] = __float2bfloat16(r < 341 ? uW[r*256 + c] : 0.f);
    if (i < 384) {
        gbp[i] = i < 341 ? gb[i] : 0.f;
        ubp[i] = i < 341 ? ub[i] : 0.f;
    }
}

__global__ void k_prep_down(const float* __restrict__ dW, bf16* __restrict__ dWb) {
    int i = blockIdx.x*256 + threadIdx.x;          // 256*384 total
    int r = i / 384, c = i % 384;
    dWb[i] = __float2bfloat16(c < 341 ? dW[r*341 + c] : 0.f);
}

// ---------------- LayerNorm 1: f32 -> bf16 ----------------
__global__ __launch_bounds__(256) void k_ln1(const float* __restrict__ x,
        const float* __restrict__ w, const float* __restrict__ b,
        bf16* __restrict__ nx) {
    int wave = threadIdx.x >> 6, lane = threadIdx.x & 63;
    long tok = (long)blockIdx.x * 4 + wave;
    float4 v = ((const float4*)(x + tok*HDIM))[lane];
    float s = v.x + v.y + v.z + v.w;
    float q = v.x*v.x + v.y*v.y + v.z*v.z + v.w*v.w;
    #pragma unroll
    for (int m = 1; m < 64; m <<= 1) { s += __shfl_xor(s, m, 64); q += __shfl_xor(q, m, 64); }
    float mean = s * (1.0f/HDIM);
    float rs = rsqrtf(q*(1.0f/HDIM) - mean*mean + 1e-5f);
    float4 wv = ((const float4*)w)[lane];
    float4 bv = ((const float4*)b)[lane];
    bf16 tmp[4];
    tmp[0] = __float2bfloat16((v.x-mean)*rs*wv.x + bv.x);
    tmp[1] = __float2bfloat16((v.y-mean)*rs*wv.y + bv.y);
    tmp[2] = __float2bfloat16((v.z-mean)*rs*wv.z + bv.z);
    tmp[3] = __float2bfloat16((v.w-mean)*rs*wv.w + bv.w);
    *(ushort4*)(nx + tok*HDIM + lane*4) = *(ushort4*)tmp;
}

// ---------------- LayerNorm 2 + residual: f16 mlp + f32 x -> f32 out ----------------
__global__ __launch_bounds__(256) void k_ln2(const f16* __restrict__ mlp,
        const float* __restrict__ x, const float* __restrict__ w,
        const float* __restrict__ b, float* __restrict__ out) {
    int wave = threadIdx.x >> 6, lane = threadIdx.x & 63;
    long tok = (long)blockIdx.x * 4 + wave;
    const f16* mr = mlp + tok*HDIM + lane*4;
    float4 v; v.x = (float)mr[0]; v.y = (float)mr[1]; v.z = (float)mr[2]; v.w = (float)mr[3];
    float s = v.x + v.y + v.z + v.w;
    float q = v.x*v.x + v.y*v.y + v.z*v.z + v.w*v.w;
    #pragma unroll
    for (int m = 1; m < 64; m <<= 1) { s += __shfl_xor(s, m, 64); q += __shfl_xor(q, m, 64); }
    float mean = s * (1.0f/HDIM);
    float rs = rsqrtf(q*(1.0f/HDIM) - mean*mean + 1e-5f);
    float4 wv = ((const float4*)w)[lane];
    float4 bv = ((const float4*)b)[lane];
    float4 xv = ((const float4*)(x + tok*HDIM))[lane];
    float4 ov;
    ov.x = (v.x-mean)*rs*wv.x + bv.x + xv.x;
    ov.y = (v.y-mean)*rs*wv.y + bv.y + xv.y;
    ov.z = (v.z-mean)*rs*wv.z + bv.z + xv.z;
    ov.w = (v.w-mean)*rs*wv.w + bv.w + xv.w;
    ((float4*)(out + tok*HDIM))[lane] = ov;
}

// ---------------- GEMM: C[M x N] = A[M x K] * B[N x K]^T + bias ----------------
// MODE_XW_F16 writes gate-interleaved layout: [m][n&255][n>>8] (4 f16 per row j).
enum { MODE_F16 = 0, MODE_GELU_F16 = 1, MODE_MUL_BF16 = 2, MODE_XW_F16 = 3 };

template<int MODE>
__global__ __launch_bounds__(256) void k_gemm(
    const bf16* __restrict__ A, const bf16* __restrict__ Bm,
    const float* __restrict__ bias, void* __restrict__ Cv,
    const f16* __restrict__ gatebuf,
    int K, int lda, int ldb, int ldc, int ldg)
{
    // BM=128, BN=64, BK=64; rows stored as 64 bf16 = 128B = 8x16B slots, XOR-swizzled
    __shared__ char Al[128*128];
    __shared__ char Bl[64*128];
    const int tid = threadIdx.x;
    const long bm = (long)blockIdx.x * 128;
    const int bn = blockIdx.y * 64;
    const int wave = tid >> 6, lane = tid & 63;
    const int wm = wave >> 1, wn = wave & 1;        // 2x2 waves, each 64x32
    const int l16 = lane & 15, lq = lane >> 4;
    f32x4 acc[4][2] = {};
    for (int k0 = 0; k0 < K; k0 += 64) {
        #pragma unroll
        for (int p = 0; p < 4; ++p) {               // A: 128 rows x 8 chunks
            int ci = tid + p*256;
            int row = ci >> 3, s = ci & 7;
            uint4 d = *(const uint4*)(A + (bm + row)*lda + k0 + s*8);
            *(uint4*)(Al + row*128 + ((s ^ (row&7))<<4)) = d;
        }
        #pragma unroll
        for (int p = 0; p < 2; ++p) {               // B: 64 rows x 8 chunks
            int ci = tid + p*256;
            int row = ci >> 3, s = ci & 7;
            uint4 d = *(const uint4*)(Bm + (long)(bn + row)*ldb + k0 + s*8);
            *(uint4*)(Bl + row*128 + ((s ^ (row&7))<<4)) = d;
        }
        __syncthreads();
        #pragma unroll
        for (int kc = 0; kc < 2; ++kc) {
            bf16x8 bf[2];
            #pragma unroll
            for (int fn = 0; fn < 2; ++fn) {
                int row = wn*32 + fn*16 + l16;
                int slot = (kc<<2) + lq;
                bf[fn] = *(const bf16x8*)(Bl + row*128 + ((slot ^ (row&7))<<4));
            }
            #pragma unroll
            for (int fm = 0; fm < 4; ++fm) {
                int row = wm*64 + fm*16 + l16;
                int slot = (kc<<2) + lq;
                bf16x8 af = *(const bf16x8*)(Al + row*128 + ((slot ^ (row&7))<<4));
                acc[fm][0] = __builtin_amdgcn_mfma_f32_16x16x32_bf16(af, bf[0], acc[fm][0], 0,0,0);
                acc[fm][1] = __builtin_amdgcn_mfma_f32_16x16x32_bf16(af, bf[1], acc[fm][1], 0,0,0);
            }
        }
        __syncthreads();
    }
    #pragma unroll
    for (int fm = 0; fm < 4; ++fm) {
        #pragma unroll
        for (int fn = 0; fn < 2; ++fn) {
            int n = bn + wn*32 + fn*16 + l16;
            float bv = bias[n];
            #pragma unroll
            for (int r = 0; r < 4; ++r) {
                long m = bm + wm*64 + fm*16 + lq*4 + r;
                float v = acc[fm][fn][r] + bv;
                if constexpr (MODE == MODE_F16) {
                    ((f16*)Cv)[m*ldc + n] = (f16)v;
                } else if constexpr (MODE == MODE_XW_F16) {
                    ((f16*)Cv)[m*ldc + ((n & 255) << 2) + (n >> 8)] = (f16)v;
                } else if constexpr (MODE == MODE_GELU_F16) {
                    ((f16*)Cv)[m*ldc + n] = (f16)gelu_tanh(v);
                } else {
                    float g = (float)gatebuf[m*ldg + n];
                    ((bf16*)Cv)[m*ldc + n] = __float2bfloat16(g * v);
                }
            }
        }
    }
}

// ---------------- sLSTM scan: 64 blocks (1 batch each), 1024 threads / 16 waves ----
// R9 structure (best measured: 1863us) + split mfma dependency chains.
// MFMA i8, 4 waves/SIMD. Wave w owns j-block [w*16, w*16+16): 4 gate-tiles x
// 4 k-mfma = 16 mfma/wave/step. Per gate, kk=0..3 accumulation is split into TWO
// independent 2-deep chains (kk01 / kk23) summed by one exact int add: halves the
// mfma chain-drain latency between the barrier-released mfma burst and dequant.
// Integer adds are associative -> bitwise-identical results to R9.
// B-frags (R8) register/AGPR-resident; A-frags = 4 broadcast ds_read_b128 of the
// 256B h ping-pong buffer. Raw s_barrier + lgkmcnt(0) per step (no vmcnt drain).
// No s_setprio (R10: harmful in barrier-locked schedules).

__global__ __launch_bounds__(1024) __attribute__((amdgpu_waves_per_eu(4, 4)))
void k_scan(const f16* __restrict__ xW, const char* __restrict__ R8,
            const float* __restrict__ rscale, bf16* __restrict__ h_out)
{
    __shared__ char hq[2][256];                      // i8 h, ping-pong
    const int tid = threadIdx.x;
    const int b    = blockIdx.x;
    const int w    = tid >> 6;                       // wave 0..15
    const int lane = tid & 63;
    const int c    = lane & 15;                      // j-column / gate-column
    const int q    = lane >> 4;                      // k lane-group (0..3)
    const int j    = w*16 + c;

    // ---- one-time: B-fragments (R8) -> 16 uint4 (AGPR-friendly) ----
    uint4 Bf[4][4];
    #pragma unroll
    for (int m = 0; m < 4; ++m) {
        #pragma unroll
        for (int kk = 0; kk < 4; ++kk)
            Bf[m][kk] = *(const uint4*)(R8 + (long)(j + 256*m)*256 + kk*64 + q*16);
    }
    float rs[4];
    #pragma unroll
    for (int m = 0; m < 4; ++m)
        rs[m] = rscale[j + 256*m] * (1.0f/127.0f);
    if (tid < 64) ((unsigned*)hq[0])[tid] = 0u;

    // gate-interleaved x rows; per-lane 8B for its j (4 q-replicas, broadcast).
    const char* xg = (const char*)xW + (long)b * TT * 2048 + j*8;
    bf16* hrow = h_out + (long)b * TT * HDIM;

    uint2 XA = *(const uint2*)(xg);                  // t=0
    uint2 XB = *(const uint2*)(xg + 2048);           // t=1
    float cst = 0.f, nst = 0.f, mst = 0.f;
    int cur = 0;
    __syncthreads();

#define SCAN_STEP(XREG, TPRE)                                                   \
    do {                                                                        \
        f16x2 xlo = __builtin_bit_cast(f16x2, XREG.x);                          \
        f16x2 xhi = __builtin_bit_cast(f16x2, XREG.y);                          \
        XREG = *(const uint2*)(xg + (long)(TPRE)*2048);                         \
        i32x4 af[4];                                                            \
        _Pragma("unroll")                                                       \
        for (int kk = 0; kk < 4; ++kk)                                          \
            af[kk] = __builtin_bit_cast(i32x4,                                  \
                         *(const uint4*)(hq[cur] + kk*64 + q*16));              \
        i32x4 a0a = {0,0,0,0}, a1a = {0,0,0,0}, a2a = {0,0,0,0}, a3a = {0,0,0,0}; \
        i32x4 a0b = {0,0,0,0}, a1b = {0,0,0,0}, a2b = {0,0,0,0}, a3b = {0,0,0,0}; \
        /* two independent 2-deep chains per gate: kk01 -> *a, kk23 -> *b */    \
        a0a = __builtin_amdgcn_mfma_i32_16x16x64_i8(af[0], __builtin_bit_cast(i32x4, Bf[0][0]), a0a, 0,0,0); \
        a1a = __builtin_amdgcn_mfma_i32_16x16x64_i8(af[0], __builtin_bit_cast(i32x4, Bf[1][0]), a1a, 0,0,0); \
        a2a = __builtin_amdgcn_mfma_i32_16x16x64_i8(af[0], __builtin_bit_cast(i32x4, Bf[2][0]), a2a, 0,0,0); \
        a3a = __builtin_amdgcn_mfma_i32_16x16x64_i8(af[0], __builtin_bit_cast(i32x4, Bf[3][0]), a3a, 0,0,0); \
        a0b = __builtin_amdgcn_mfma_i32_16x16x64_i8(af[2], __builtin_bit_cast(i32x4, Bf[0][2]), a0b, 0,0,0); \
        a1b = __builtin_amdgcn_mfma_i32_16x16x64_i8(af[2], __builtin_bit_cast(i32x4, Bf[1][2]), a1b, 0,0,0); \
        a2b = __builtin_amdgcn_mfma_i32_16x16x64_i8(af[2], __builtin_bit_cast(i32x4, Bf[2][2]), a2b, 0,0,0); \
        a3b = __builtin_amdgcn_mfma_i32_16x16x64_i8(af[2], __builtin_bit_cast(i32x4, Bf[3][2]), a3b, 0,0,0); \
        a0a = __builtin_amdgcn_mfma_i32_16x16x64_i8(af[1], __builtin_bit_cast(i32x4, Bf[0][1]), a0a, 0,0,0); \
        a1a = __builtin_amdgcn_mfma_i32_16x16x64_i8(af[1], __builtin_bit_cast(i32x4, Bf[1][1]), a1a, 0,0,0); \
        a2a = __builtin_amdgcn_mfma_i32_16x16x64_i8(af[1], __builtin_bit_cast(i32x4, Bf[2][1]), a2a, 0,0,0); \
        a3a = __builtin_amdgcn_mfma_i32_16x16x64_i8(af[1], __builtin_bit_cast(i32x4, Bf[3][1]), a3a, 0,0,0); \
        a0b = __builtin_amdgcn_mfma_i32_16x16x64_i8(af[3], __builtin_bit_cast(i32x4, Bf[0][3]), a0b, 0,0,0); \
        a1b = __builtin_amdgcn_mfma_i32_16x16x64_i8(af[3], __builtin_bit_cast(i32x4, Bf[1][3]), a1b, 0,0,0); \
        a2b = __builtin_amdgcn_mfma_i32_16x16x64_i8(af[3], __builtin_bit_cast(i32x4, Bf[2][3]), a2b, 0,0,0); \
        a3b = __builtin_amdgcn_mfma_i32_16x16x64_i8(af[3], __builtin_bit_cast(i32x4, Bf[3][3]), a3b, 0,0,0); \
        float pz = rs[0]*(float)(a0a[0] + a0b[0]) + (float)xlo[0];              \
        float pi = rs[1]*(float)(a1a[0] + a1b[0]) + (float)xlo[1];              \
        float pf = rs[2]*(float)(a2a[0] + a2b[0]) + (float)xhi[0];              \
        float po = rs[3]*(float)(a3a[0] + a3b[0]) + (float)xhi[1];              \
        float e = __expf(-2.0f * fabsf(pz));                                    \
        float z = copysignf((1.0f - e) / (1.0f + e), pz);                       \
        float o = 1.0f / (1.0f + __expf(-po));                                  \
        float mn = fmaxf(pf + mst, pi);                                         \
        float ig = __expf(pi - mn);                                             \
        float fg = __expf(pf + mst - mn);                                       \
        cst = fg*cst + ig*z;                                                    \
        nst = fg*nst + ig;                                                      \
        mst = mn;                                                               \
        float h = o * (cst / nst);                                              \
        if (q == 0) {                                                           \
            hq[cur^1][j] = (char)(int)rintf(h * 127.f);                         \
            hrow[j] = __float2bfloat16(h);                                      \
        }                                                                       \
        __builtin_amdgcn_sched_barrier(0);                                      \
        asm volatile("s_waitcnt lgkmcnt(0)" ::: "memory");                      \
        __builtin_amdgcn_s_barrier();                                           \
        __builtin_amdgcn_sched_barrier(0);                                      \
        cur ^= 1;                                                               \
        hrow += HDIM;                                                           \
    } while (0)

    for (int t = 0; t < TT; t += 2) {
        SCAN_STEP(XA, t + 2);
        SCAN_STEP(XB, t + 3);
    }
#undef SCAN_STEP
}

// ---------------- launch ----------------
extern "C" void kernel_launch(void* const* d_in, const int* in_sizes, int n_in,
                              void* d_out, int out_size, void* d_ws, size_t ws_size,
                              hipStream_t stream) {
    const float* x     = (const float*)d_in[0];
    const float* ln1w  = (const float*)d_in[1];
    const float* ln1b  = (const float*)d_in[2];
    const float* W     = (const float*)d_in[3];
    const float* R     = (const float*)d_in[4];
    const float* bg    = (const float*)d_in[5];
    const float* upW   = (const float*)d_in[6];
    const float* upb   = (const float*)d_in[7];
    const float* gateW = (const float*)d_in[8];
    const float* gateb = (const float*)d_in[9];
    const float* downW = (const float*)d_in[10];
    const float* downb = (const float*)d_in[11];
    const float* ln2w  = (const float*)d_in[12];
    const float* ln2b  = (const float*)d_in[13];

    char* ws = (char*)d_ws;
    size_t off = 0;
    auto alloc = [&](size_t bytes) { char* p = ws + off; off += (bytes + 255) & ~255ULL; return p; };
    f16*  mlp16   = (f16*)alloc((size_t)NTOK*HDIM*2);     // holds nx first, then mlp (disjoint lifetimes)
    char* regionB = alloc((size_t)NTOK*G4*2);             // xW, then gate_out+prod
    bf16* h       = (bf16*)alloc((size_t)NTOK*HDIM*2);
    bf16* Wb      = (bf16*)alloc(262144*2);
    char* R8      = (char*)alloc(262144);
    float* rscale = (float*)alloc(1024*4);
    bf16* gWb     = (bf16*)alloc((size_t)MPAD*256*2);
    bf16* uWb     = (bf16*)alloc((size_t)MPAD*256*2);
    bf16* dWb     = (bf16*)alloc((size_t)256*MPAD*2);
    float* gbp    = (float*)alloc(MPAD*4);
    float* ubp    = (float*)alloc(MPAD*4);

    bf16* nx       = (bf16*)mlp16;                        // phase 1 use of that region
    f16*  xWb      = (f16*)regionB;                       // 131072 x 1024 f16 (gate-interleaved)
    f16*  gate_out = (f16*)regionB;                       // reuse after scan: 131072 x 384 f16
    bf16* prod     = (bf16*)(regionB + (size_t)NTOK*MPAD*2);

    k_prep_w   <<<1024, 256, 0, stream>>>(W, Wb);
    k_prep_r8  <<<256, 256, 0, stream>>>(R, R8, rscale);
    k_prep_gu  <<<384, 256, 0, stream>>>(gateW, upW, gateb, upb, gWb, uWb, gbp, ubp);
    k_prep_down<<<384, 256, 0, stream>>>(downW, dWb);
    k_ln1      <<<NTOK/4, 256, 0, stream>>>(x, ln1w, ln1b, nx);
    // xW = nx @ W^T + b   (f16, gate-interleaved per token)
    k_gemm<MODE_XW_F16><<<dim3(1024, 16), 256, 0, stream>>>(nx, Wb, bg, xWb, nullptr, 256, 256, 256, 1024, 0);
    // sequential sLSTM scan (MFMA i8, 16 waves, split chains)
    k_scan     <<<64, 1024, 0, stream>>>(xWb, R8, rscale, h);
    // gate = gelu(h @ gateW^T + gate_b)  (f16)
    k_gemm<MODE_GELU_F16><<<dim3(1024, 6), 256, 0, stream>>>(h, gWb, gbp, gate_out, nullptr, 256, 256, 256, MPAD, 0);
    // prod = gate * (h @ upW^T + up_b)   (bf16, padded cols auto-zero)
    k_gemm<MODE_MUL_BF16><<<dim3(1024, 6), 256, 0, stream>>>(h, uWb, ubp, prod, gate_out, 256, 256, 256, MPAD, MPAD);
    // mlp = prod @ downW^T + down_b      (f16 out, K=384)
    k_gemm<MODE_F16><<<dim3(1024, 4), 256, 0, stream>>>(prod, dWb, downb, mlp16, nullptr, MPAD, MPAD, MPAD, HDIM, 0);
    // out = LN(mlp) + x
    k_ln2      <<<NTOK/4, 256, 0, stream>>>(mlp16, x, ln2w, ln2b, (float*)d_out);
}

// Round 12
// 2615.424 us; speedup vs baseline: 1.0874x; 1.0003x over previous
//
#include <hip/hip_runtime.h>
#include <hip/hip_bf16.h>
#include <hip/hip_fp16.h>

typedef _Float16 f16;
typedef __hip_bfloat16 bf16;
typedef short bf16x8 __attribute__((ext_vector_type(8)));
typedef float f32x4 __attribute__((ext_vector_type(4)));
typedef int i32x4 __attribute__((ext_vector_type(4)));
typedef _Float16 f16x2 __attribute__((ext_vector_type(2)));

#define HDIM 256
#define G4   1024
#define TT   2048
#define NB   64
#define NTOK (64*2048)
#define MPAD 384   // 341 padded to 384 (6 x 64)

// ---------------- helpers ----------------
__device__ __forceinline__ float gelu_tanh(float x) {
    // jax.nn.gelu default (approximate=True)
    float x3 = x*x*x;
    float t = tanhf(0.7978845608028654f * (x + 0.044715f * x3));
    return 0.5f * x * (1.0f + t);
}

// ---------------- prep: dtype conversion + padding ----------------
__global__ void k_prep_w(const float* __restrict__ W, bf16* __restrict__ Wb) {
    int i = blockIdx.x*256 + threadIdx.x;          // 262144 total
    Wb[i] = __float2bfloat16(W[i]);
}

// R -> int8 with per-gate-row scale. One wave per row (256 f32 -> 256 i8).
__global__ __launch_bounds__(256) void k_prep_r8(const float* __restrict__ R,
        char* __restrict__ R8, float* __restrict__ rscale) {
    int wave = threadIdx.x >> 6, lane = threadIdx.x & 63;
    int g = blockIdx.x*4 + wave;
    float4 v = ((const float4*)(R + (long)g*256))[lane];
    float mx = fmaxf(fmaxf(fabsf(v.x), fabsf(v.y)), fmaxf(fabsf(v.z), fabsf(v.w)));
    #pragma unroll
    for (int m = 1; m < 64; m <<= 1) mx = fmaxf(mx, __shfl_xor(mx, m, 64));
    float inv = (mx > 0.f) ? 127.f/mx : 0.f;
    int q0 = (int)rintf(v.x*inv), q1 = (int)rintf(v.y*inv);
    int q2 = (int)rintf(v.z*inv), q3 = (int)rintf(v.w*inv);
    unsigned packed = (q0 & 0xff) | ((q1 & 0xff) << 8) | ((q2 & 0xff) << 16) | ((q3 & 0xff) << 24);
    ((unsigned*)(R8 + (long)g*256))[lane] = packed;
    if (lane == 0) rscale[g] = mx * (1.0f/127.f);
}

__global__ void k_prep_gu(const float* __restrict__ gW, const float* __restrict__ uW,
                          const float* __restrict__ gb, const float* __restrict__ ub,
                          bf16* __restrict__ gWb, bf16* __restrict__ uWb,
                          float* __restrict__ gbp, float* __restrict__ ubp) {
    int i = blockIdx.x*256 + threadIdx.x;          // 384*256 total
    int r = i >> 8, c = i & 255;
    gWb[i] = __float2bfloat16(r < 341 ? gW[r*256 + c] : 0.f);
    uWb[i] = __float2bfloat16(r < 341 ? uW[r*256 + c] : 0.f);
    if (i < 384) {
        gbp[i] = i < 341 ? gb[i] : 0.f;
        ubp[i] = i < 341 ? ub[i] : 0.f;
    }
}

__global__ void k_prep_down(const float* __restrict__ dW, bf16* __restrict__ dWb) {
    int i = blockIdx.x*256 + threadIdx.x;          // 256*384 total
    int r = i / 384, c = i % 384;
    dWb[i] = __float2bfloat16(c < 341 ? dW[r*341 + c] : 0.f);
}

// ---------------- LayerNorm 1: f32 -> bf16 ----------------
__global__ __launch_bounds__(256) void k_ln1(const float* __restrict__ x,
        const float* __restrict__ w, const float* __restrict__ b,
        bf16* __restrict__ nx) {
    int wave = threadIdx.x >> 6, lane = threadIdx.x & 63;
    long tok = (long)blockIdx.x * 4 + wave;
    float4 v = ((const float4*)(x + tok*HDIM))[lane];
    float s = v.x + v.y + v.z + v.w;
    float q = v.x*v.x + v.y*v.y + v.z*v.z + v.w*v.w;
    #pragma unroll
    for (int m = 1; m < 64; m <<= 1) { s += __shfl_xor(s, m, 64); q += __shfl_xor(q, m, 64); }
    float mean = s * (1.0f/HDIM);
    float rs = rsqrtf(q*(1.0f/HDIM) - mean*mean + 1e-5f);
    float4 wv = ((const float4*)w)[lane];
    float4 bv = ((const float4*)b)[lane];
    bf16 tmp[4];
    tmp[0] = __float2bfloat16((v.x-mean)*rs*wv.x + bv.x);
    tmp[1] = __float2bfloat16((v.y-mean)*rs*wv.y + bv.y);
    tmp[2] = __float2bfloat16((v.z-mean)*rs*wv.z + bv.z);
    tmp[3] = __float2bfloat16((v.w-mean)*rs*wv.w + bv.w);
    *(ushort4*)(nx + tok*HDIM + lane*4) = *(ushort4*)tmp;
}

// ---------------- LayerNorm 2 + residual: f16 mlp + f32 x -> f32 out ----------------
__global__ __launch_bounds__(256) void k_ln2(const f16* __restrict__ mlp,
        const float* __restrict__ x, const float* __restrict__ w,
        const float* __restrict__ b, float* __restrict__ out) {
    int wave = threadIdx.x >> 6, lane = threadIdx.x & 63;
    long tok = (long)blockIdx.x * 4 + wave;
    const f16* mr = mlp + tok*HDIM + lane*4;
    float4 v; v.x = (float)mr[0]; v.y = (float)mr[1]; v.z = (float)mr[2]; v.w = (float)mr[3];
    float s = v.x + v.y + v.z + v.w;
    float q = v.x*v.x + v.y*v.y + v.z*v.z + v.w*v.w;
    #pragma unroll
    for (int m = 1; m < 64; m <<= 1) { s += __shfl_xor(s, m, 64); q += __shfl_xor(q, m, 64); }
    float mean = s * (1.0f/HDIM);
    float rs = rsqrtf(q*(1.0f/HDIM) - mean*mean + 1e-5f);
    float4 wv = ((const float4*)w)[lane];
    float4 bv = ((const float4*)b)[lane];
    float4 xv = ((const float4*)(x + tok*HDIM))[lane];
    float4 ov;
    ov.x = (v.x-mean)*rs*wv.x + bv.x + xv.x;
    ov.y = (v.y-mean)*rs*wv.y + bv.y + xv.y;
    ov.z = (v.z-mean)*rs*wv.z + bv.z + xv.z;
    ov.w = (v.w-mean)*rs*wv.w + bv.w + xv.w;
    ((float4*)(out + tok*HDIM))[lane] = ov;
}

// ---------------- GEMM: C[M x N] = A[M x K] * B[N x K]^T + bias ----------------
// MODE_XW_F16 writes gate-interleaved layout: [m][n&255][n>>8] (4 f16 per row j).
enum { MODE_F16 = 0, MODE_GELU_F16 = 1, MODE_MUL_BF16 = 2, MODE_XW_F16 = 3 };

template<int MODE>
__global__ __launch_bounds__(256) void k_gemm(
    const bf16* __restrict__ A, const bf16* __restrict__ Bm,
    const float* __restrict__ bias, void* __restrict__ Cv,
    const f16* __restrict__ gatebuf,
    int K, int lda, int ldb, int ldc, int ldg)
{
    // BM=128, BN=64, BK=64; rows stored as 64 bf16 = 128B = 8x16B slots, XOR-swizzled
    __shared__ char Al[128*128];
    __shared__ char Bl[64*128];
    const int tid = threadIdx.x;
    const long bm = (long)blockIdx.x * 128;
    const int bn = blockIdx.y * 64;
    const int wave = tid >> 6, lane = tid & 63;
    const int wm = wave >> 1, wn = wave & 1;        // 2x2 waves, each 64x32
    const int l16 = lane & 15, lq = lane >> 4;
    f32x4 acc[4][2] = {};
    for (int k0 = 0; k0 < K; k0 += 64) {
        #pragma unroll
        for (int p = 0; p < 4; ++p) {               // A: 128 rows x 8 chunks
            int ci = tid + p*256;
            int row = ci >> 3, s = ci & 7;
            uint4 d = *(const uint4*)(A + (bm + row)*lda + k0 + s*8);
            *(uint4*)(Al + row*128 + ((s ^ (row&7))<<4)) = d;
        }
        #pragma unroll
        for (int p = 0; p < 2; ++p) {               // B: 64 rows x 8 chunks
            int ci = tid + p*256;
            int row = ci >> 3, s = ci & 7;
            uint4 d = *(const uint4*)(Bm + (long)(bn + row)*ldb + k0 + s*8);
            *(uint4*)(Bl + row*128 + ((s ^ (row&7))<<4)) = d;
        }
        __syncthreads();
        #pragma unroll
        for (int kc = 0; kc < 2; ++kc) {
            bf16x8 bf[2];
            #pragma unroll
            for (int fn = 0; fn < 2; ++fn) {
                int row = wn*32 + fn*16 + l16;
                int slot = (kc<<2) + lq;
                bf[fn] = *(const bf16x8*)(Bl + row*128 + ((slot ^ (row&7))<<4));
            }
            #pragma unroll
            for (int fm = 0; fm < 4; ++fm) {
                int row = wm*64 + fm*16 + l16;
                int slot = (kc<<2) + lq;
                bf16x8 af = *(const bf16x8*)(Al + row*128 + ((slot ^ (row&7))<<4));
                acc[fm][0] = __builtin_amdgcn_mfma_f32_16x16x32_bf16(af, bf[0], acc[fm][0], 0,0,0);
                acc[fm][1] = __builtin_amdgcn_mfma_f32_16x16x32_bf16(af, bf[1], acc[fm][1], 0,0,0);
            }
        }
        __syncthreads();
    }
    #pragma unroll
    for (int fm = 0; fm < 4; ++fm) {
        #pragma unroll
        for (int fn = 0; fn < 2; ++fn) {
            int n = bn + wn*32 + fn*16 + l16;
            float bv = bias[n];
            #pragma unroll
            for (int r = 0; r < 4; ++r) {
                long m = bm + wm*64 + fm*16 + lq*4 + r;
                float v = acc[fm][fn][r] + bv;
                if constexpr (MODE == MODE_F16) {
                    ((f16*)Cv)[m*ldc + n] = (f16)v;
                } else if constexpr (MODE == MODE_XW_F16) {
                    ((f16*)Cv)[m*ldc + ((n & 255) << 2) + (n >> 8)] = (f16)v;
                } else if constexpr (MODE == MODE_GELU_F16) {
                    ((f16*)Cv)[m*ldc + n] = (f16)gelu_tanh(v);
                } else {
                    float g = (float)gatebuf[m*ldg + n];
                    ((bf16*)Cv)[m*ldc + n] = __float2bfloat16(g * v);
                }
            }
        }
    }
}

// ---------------- sLSTM scan: 64 blocks (1 batch each), 1024 threads / 16 waves ----
// R11 structure + issue-slot diet:
//  * ZERO accumulator trick: chain-start mfma consumes a loop-invariant zero
//    i32x4 as C -> no per-step acc zero-init movs (was ~32 v_mov/wave/step on
//    the shared issue port).
//  * single sched_barrier fence (post-barrier only; ds_write ordering is held
//    by the asm memory clobber on the lgkmcnt wait).
// MFMA i8, 4 waves/SIMD; wave w owns j-block [w*16, w*16+16): 4 gate-tiles x
// (2 independent 2-deep k-chains) = 16 mfma/wave/step. B-frags register/AGPR
// resident; A-frags = 4 broadcast ds_read_b128 of the 256B h ping-pong buffer.
// Raw s_barrier + lgkmcnt(0) per step (no vmcnt drain).

__global__ __launch_bounds__(1024) __attribute__((amdgpu_waves_per_eu(4, 4)))
void k_scan(const f16* __restrict__ xW, const char* __restrict__ R8,
            const float* __restrict__ rscale, bf16* __restrict__ h_out)
{
    __shared__ char hq[2][256];                      // i8 h, ping-pong
    const int tid = threadIdx.x;
    const int b    = blockIdx.x;
    const int w    = tid >> 6;                       // wave 0..15
    const int lane = tid & 63;
    const int c    = lane & 15;                      // j-column / gate-column
    const int q    = lane >> 4;                      // k lane-group (0..3)
    const int j    = w*16 + c;

    // ---- one-time: B-fragments (R8) -> 16 uint4 (AGPR-friendly) ----
    uint4 Bf[4][4];
    #pragma unroll
    for (int m = 0; m < 4; ++m) {
        #pragma unroll
        for (int kk = 0; kk < 4; ++kk)
            Bf[m][kk] = *(const uint4*)(R8 + (long)(j + 256*m)*256 + kk*64 + q*16);
    }
    float rs[4];
    #pragma unroll
    for (int m = 0; m < 4; ++m)
        rs[m] = rscale[j + 256*m] * (1.0f/127.0f);
    if (tid < 64) ((unsigned*)hq[0])[tid] = 0u;

    // gate-interleaved x rows; per-lane 8B for its j (4 q-replicas, broadcast).
    const char* xg = (const char*)xW + (long)b * TT * 2048 + j*8;
    bf16* hrow = h_out + (long)b * TT * HDIM;

    uint2 XA = *(const uint2*)(xg);                  // t=0
    uint2 XB = *(const uint2*)(xg + 2048);           // t=1
    const char* xp = xg + 2*2048;                    // next prefetch addr (t=2)
    float cst = 0.f, nst = 0.f, mst = 0.f;
    int cur = 0;
    const i32x4 ZERO = {0,0,0,0};                    // loop-invariant chain seed
    __syncthreads();

#define SCAN_STEP(XREG)                                                         \
    do {                                                                        \
        f16x2 xlo = __builtin_bit_cast(f16x2, XREG.x);                          \
        f16x2 xhi = __builtin_bit_cast(f16x2, XREG.y);                          \
        XREG = *(const uint2*)xp;                                               \
        xp += 2048;                                                             \
        i32x4 af[4];                                                            \
        _Pragma("unroll")                                                       \
        for (int kk = 0; kk < 4; ++kk)                                          \
            af[kk] = __builtin_bit_cast(i32x4,                                  \
                         *(const uint4*)(hq[cur] + kk*64 + q*16));              \
        /* two independent 2-deep chains per gate, seeded from ZERO (no movs) */\
        i32x4 a0a = __builtin_amdgcn_mfma_i32_16x16x64_i8(af[0], __builtin_bit_cast(i32x4, Bf[0][0]), ZERO, 0,0,0); \
        i32x4 a1a = __builtin_amdgcn_mfma_i32_16x16x64_i8(af[0], __builtin_bit_cast(i32x4, Bf[1][0]), ZERO, 0,0,0); \
        i32x4 a2a = __builtin_amdgcn_mfma_i32_16x16x64_i8(af[0], __builtin_bit_cast(i32x4, Bf[2][0]), ZERO, 0,0,0); \
        i32x4 a3a = __builtin_amdgcn_mfma_i32_16x16x64_i8(af[0], __builtin_bit_cast(i32x4, Bf[3][0]), ZERO, 0,0,0); \
        i32x4 a0b = __builtin_amdgcn_mfma_i32_16x16x64_i8(af[2], __builtin_bit_cast(i32x4, Bf[0][2]), ZERO, 0,0,0); \
        i32x4 a1b = __builtin_amdgcn_mfma_i32_16x16x64_i8(af[2], __builtin_bit_cast(i32x4, Bf[1][2]), ZERO, 0,0,0); \
        i32x4 a2b = __builtin_amdgcn_mfma_i32_16x16x64_i8(af[2], __builtin_bit_cast(i32x4, Bf[2][2]), ZERO, 0,0,0); \
        i32x4 a3b = __builtin_amdgcn_mfma_i32_16x16x64_i8(af[2], __builtin_bit_cast(i32x4, Bf[3][2]), ZERO, 0,0,0); \
        a0a = __builtin_amdgcn_mfma_i32_16x16x64_i8(af[1], __builtin_bit_cast(i32x4, Bf[0][1]), a0a, 0,0,0); \
        a1a = __builtin_amdgcn_mfma_i32_16x16x64_i8(af[1], __builtin_bit_cast(i32x4, Bf[1][1]), a1a, 0,0,0); \
        a2a = __builtin_amdgcn_mfma_i32_16x16x64_i8(af[1], __builtin_bit_cast(i32x4, Bf[2][1]), a2a, 0,0,0); \
        a3a = __builtin_amdgcn_mfma_i32_16x16x64_i8(af[1], __builtin_bit_cast(i32x4, Bf[3][1]), a3a, 0,0,0); \
        a0b = __builtin_amdgcn_mfma_i32_16x16x64_i8(af[3], __builtin_bit_cast(i32x4, Bf[0][3]), a0b, 0,0,0); \
        a1b = __builtin_amdgcn_mfma_i32_16x16x64_i8(af[3], __builtin_bit_cast(i32x4, Bf[1][3]), a1b, 0,0,0); \
        a2b = __builtin_amdgcn_mfma_i32_16x16x64_i8(af[3], __builtin_bit_cast(i32x4, Bf[2][3]), a2b, 0,0,0); \
        a3b = __builtin_amdgcn_mfma_i32_16x16x64_i8(af[3], __builtin_bit_cast(i32x4, Bf[3][3]), a3b, 0,0,0); \
        float pz = rs[0]*(float)(a0a[0] + a0b[0]) + (float)xlo[0];              \
        float pi = rs[1]*(float)(a1a[0] + a1b[0]) + (float)xlo[1];              \
        float pf = rs[2]*(float)(a2a[0] + a2b[0]) + (float)xhi[0];              \
        float po = rs[3]*(float)(a3a[0] + a3b[0]) + (float)xhi[1];              \
        float e = __expf(-2.0f * fabsf(pz));                                    \
        float z = copysignf((1.0f - e) / (1.0f + e), pz);                       \
        float o = 1.0f / (1.0f + __expf(-po));                                  \
        float mn = fmaxf(pf + mst, pi);                                         \
        float ig = __expf(pi - mn);                                             \
        float fg = __expf(pf + mst - mn);                                       \
        cst = fg*cst + ig*z;                                                    \
        nst = fg*nst + ig;                                                      \
        mst = mn;                                                               \
        float h = o * (cst / nst);                                              \
        if (q == 0) {                                                           \
            hq[cur^1][j] = (char)(int)rintf(h * 127.f);                         \
            hrow[j] = __float2bfloat16(h);                                      \
        }                                                                       \
        asm volatile("s_waitcnt lgkmcnt(0)" ::: "memory");                      \
        __builtin_amdgcn_s_barrier();                                           \
        __builtin_amdgcn_sched_barrier(0);                                      \
        cur ^= 1;                                                               \
        hrow += HDIM;                                                           \
    } while (0)

    for (int t = 0; t < TT; t += 2) {
        SCAN_STEP(XA);
        SCAN_STEP(XB);
    }
#undef SCAN_STEP
}

// ---------------- launch ----------------
extern "C" void kernel_launch(void* const* d_in, const int* in_sizes, int n_in,
                              void* d_out, int out_size, void* d_ws, size_t ws_size,
                              hipStream_t stream) {
    const float* x     = (const float*)d_in[0];
    const float* ln1w  = (const float*)d_in[1];
    const float* ln1b  = (const float*)d_in[2];
    const float* W     = (const float*)d_in[3];
    const float* R     = (const float*)d_in[4];
    const float* bg    = (const float*)d_in[5];
    const float* upW   = (const float*)d_in[6];
    const float* upb   = (const float*)d_in[7];
    const float* gateW = (const float*)d_in[8];
    const float* gateb = (const float*)d_in[9];
    const float* downW = (const float*)d_in[10];
    const float* downb = (const float*)d_in[11];
    const float* ln2w  = (const float*)d_in[12];
    const float* ln2b  = (const float*)d_in[13];

    char* ws = (char*)d_ws;
    size_t off = 0;
    auto alloc = [&](size_t bytes) { char* p = ws + off; off += (bytes + 255) & ~255ULL; return p; };
    f16*  mlp16   = (f16*)alloc((size_t)NTOK*HDIM*2);     // holds nx first, then mlp (disjoint lifetimes)
    char* regionB = alloc((size_t)NTOK*G4*2);             // xW, then gate_out+prod
    bf16* h       = (bf16*)alloc((size_t)NTOK*HDIM*2);
    bf16* Wb      = (bf16*)alloc(262144*2);
    char* R8      = (char*)alloc(262144);
    float* rscale = (float*)alloc(1024*4);
    bf16* gWb     = (bf16*)alloc((size_t)MPAD*256*2);
    bf16* uWb     = (bf16*)alloc((size_t)MPAD*256*2);
    bf16* dWb     = (bf16*)alloc((size_t)256*MPAD*2);
    float* gbp    = (float*)alloc(MPAD*4);
    float* ubp    = (float*)alloc(MPAD*4);

    bf16* nx       = (bf16*)mlp16;                        // phase 1 use of that region
    f16*  xWb      = (f16*)regionB;                       // 131072 x 1024 f16 (gate-interleaved)
    f16*  gate_out = (f16*)regionB;                       // reuse after scan: 131072 x 384 f16
    bf16* prod     = (bf16*)(regionB + (size_t)NTOK*MPAD*2);

    k_prep_w   <<<1024, 256, 0, stream>>>(W, Wb);
    k_prep_r8  <<<256, 256, 0, stream>>>(R, R8, rscale);
    k_prep_gu  <<<384, 256, 0, stream>>>(gateW, upW, gateb, upb, gWb, uWb, gbp, ubp);
    k_prep_down<<<384, 256, 0, stream>>>(downW, dWb);
    k_ln1      <<<NTOK/4, 256, 0, stream>>>(x, ln1w, ln1b, nx);
    // xW = nx @ W^T + b   (f16, gate-interleaved per token)
    k_gemm<MODE_XW_F16><<<dim3(1024, 16), 256, 0, stream>>>(nx, Wb, bg, xWb, nullptr, 256, 256, 256, 1024, 0);
    // sequential sLSTM scan (MFMA i8, 16 waves, split chains, zero-seeded)
    k_scan     <<<64, 1024, 0, stream>>>(xWb, R8, rscale, h);
    // gate = gelu(h @ gateW^T + gate_b)  (f16)
    k_gemm<MODE_GELU_F16><<<dim3(1024, 6), 256, 0, stream>>>(h, gWb, gbp, gate_out, nullptr, 256, 256, 256, MPAD, 0);
    // prod = gate * (h @ upW^T + up_b)   (bf16, padded cols auto-zero)
    k_gemm<MODE_MUL_BF16><<<dim3(1024, 6), 256, 0, stream>>>(h, uWb, ubp, prod, gate_out, 256, 256, 256, MPAD, MPAD);
    // mlp = prod @ downW^T + down_b      (f16 out, K=384)
    k_gemm<MODE_F16><<<dim3(1024, 4), 256, 0, stream>>>(prod, dWb, downb, mlp16, nullptr, MPAD, MPAD, MPAD, HDIM, 0);
    // out = LN(mlp) + x
    k_ln2      <<<NTOK/4, 256, 0, stream>>>(mlp16, x, ln2w, ln2b, (float*)d_out);
}

// Round 13
// 2565.156 us; speedup vs baseline: 1.1088x; 1.0196x over previous
//
#include <hip/hip_runtime.h>
#include <hip/hip_bf16.h>
#include <hip/hip_fp16.h>

typedef _Float16 f16;
typedef __hip_bfloat16 bf16;
typedef short bf16x8 __attribute__((ext_vector_type(8)));
typedef float f32x4 __attribute__((ext_vector_type(4)));
typedef int i32x4 __attribute__((ext_vector_type(4)));
typedef _Float16 f16x2 __attribute__((ext_vector_type(2)));

#define HDIM 256
#define G4   1024
#define TT   2048
#define NB   64
#define NTOK (64*2048)
#define MPAD 384   // 341 padded to 384 (6 x 64)

// ---------------- helpers ----------------
__device__ __forceinline__ float gelu_tanh(float x) {
    // jax.nn.gelu default (approximate=True)
    float x3 = x*x*x;
    float t = tanhf(0.7978845608028654f * (x + 0.044715f * x3));
    return 0.5f * x * (1.0f + t);
}

// ---------------- prep: dtype conversion + padding ----------------
__global__ void k_prep_w(const float* __restrict__ W, bf16* __restrict__ Wb) {
    int i = blockIdx.x*256 + threadIdx.x;          // 262144 total
    Wb[i] = __float2bfloat16(W[i]);
}

// R -> int8 with per-gate-row scale. One wave per row (256 f32 -> 256 i8).
__global__ __launch_bounds__(256) void k_prep_r8(const float* __restrict__ R,
        char* __restrict__ R8, float* __restrict__ rscale) {
    int wave = threadIdx.x >> 6, lane = threadIdx.x & 63;
    int g = blockIdx.x*4 + wave;
    float4 v = ((const float4*)(R + (long)g*256))[lane];
    float mx = fmaxf(fmaxf(fabsf(v.x), fabsf(v.y)), fmaxf(fabsf(v.z), fabsf(v.w)));
    #pragma unroll
    for (int m = 1; m < 64; m <<= 1) mx = fmaxf(mx, __shfl_xor(mx, m, 64));
    float inv = (mx > 0.f) ? 127.f/mx : 0.f;
    int q0 = (int)rintf(v.x*inv), q1 = (int)rintf(v.y*inv);
    int q2 = (int)rintf(v.z*inv), q3 = (int)rintf(v.w*inv);
    unsigned packed = (q0 & 0xff) | ((q1 & 0xff) << 8) | ((q2 & 0xff) << 16) | ((q3 & 0xff) << 24);
    ((unsigned*)(R8 + (long)g*256))[lane] = packed;
    if (lane == 0) rscale[g] = mx * (1.0f/127.f);
}

__global__ void k_prep_gu(const float* __restrict__ gW, const float* __restrict__ uW,
                          const float* __restrict__ gb, const float* __restrict__ ub,
                          bf16* __restrict__ gWb, bf16* __restrict__ uWb,
                          float* __restrict__ gbp, float* __restrict__ ubp) {
    int i = blockIdx.x*256 + threadIdx.x;          // 384*256 total
    int r = i >> 8, c = i & 255;
    gWb[i] = __float2bfloat16(r < 341 ? gW[r*256 + c] : 0.f);
    uWb[i] = __float2bfloat16(r < 341 ? uW[r*256 + c] : 0.f);
    if (i < 384) {
        gbp[i] = i < 341 ? gb[i] : 0.f;
        ubp[i] = i < 341 ? ub[i] : 0.f;
    }
}

__global__ void k_prep_down(const float* __restrict__ dW, bf16* __restrict__ dWb) {
    int i = blockIdx.x*256 + threadIdx.x;          // 256*384 total
    int r = i / 384, c = i % 384;
    dWb[i] = __float2bfloat16(c < 341 ? dW[r*341 + c] : 0.f);
}

// ---------------- LayerNorm 1: f32 -> bf16 ----------------
__global__ __launch_bounds__(256) void k_ln1(const float* __restrict__ x,
        const float* __restrict__ w, const float* __restrict__ b,
        bf16* __restrict__ nx) {
    int wave = threadIdx.x >> 6, lane = threadIdx.x & 63;
    long tok = (long)blockIdx.x * 4 + wave;
    float4 v = ((const float4*)(x + tok*HDIM))[lane];
    float s = v.x + v.y + v.z + v.w;
    float q = v.x*v.x + v.y*v.y + v.z*v.z + v.w*v.w;
    #pragma unroll
    for (int m = 1; m < 64; m <<= 1) { s += __shfl_xor(s, m, 64); q += __shfl_xor(q, m, 64); }
    float mean = s * (1.0f/HDIM);
    float rs = rsqrtf(q*(1.0f/HDIM) - mean*mean + 1e-5f);
    float4 wv = ((const float4*)w)[lane];
    float4 bv = ((const float4*)b)[lane];
    bf16 tmp[4];
    tmp[0] = __float2bfloat16((v.x-mean)*rs*wv.x + bv.x);
    tmp[1] = __float2bfloat16((v.y-mean)*rs*wv.y + bv.y);
    tmp[2] = __float2bfloat16((v.z-mean)*rs*wv.z + bv.z);
    tmp[3] = __float2bfloat16((v.w-mean)*rs*wv.w + bv.w);
    *(ushort4*)(nx + tok*HDIM + lane*4) = *(ushort4*)tmp;
}

// ---------------- LayerNorm 2 + residual: f16 mlp + f32 x -> f32 out ----------------
__global__ __launch_bounds__(256) void k_ln2(const f16* __restrict__ mlp,
        const float* __restrict__ x, const float* __restrict__ w,
        const float* __restrict__ b, float* __restrict__ out) {
    int wave = threadIdx.x >> 6, lane = threadIdx.x & 63;
    long tok = (long)blockIdx.x * 4 + wave;
    const f16* mr = mlp + tok*HDIM + lane*4;
    float4 v; v.x = (float)mr[0]; v.y = (float)mr[1]; v.z = (float)mr[2]; v.w = (float)mr[3];
    float s = v.x + v.y + v.z + v.w;
    float q = v.x*v.x + v.y*v.y + v.z*v.z + v.w*v.w;
    #pragma unroll
    for (int m = 1; m < 64; m <<= 1) { s += __shfl_xor(s, m, 64); q += __shfl_xor(q, m, 64); }
    float mean = s * (1.0f/HDIM);
    float rs = rsqrtf(q*(1.0f/HDIM) - mean*mean + 1e-5f);
    float4 wv = ((const float4*)w)[lane];
    float4 bv = ((const float4*)b)[lane];
    float4 xv = ((const float4*)(x + tok*HDIM))[lane];
    float4 ov;
    ov.x = (v.x-mean)*rs*wv.x + bv.x + xv.x;
    ov.y = (v.y-mean)*rs*wv.y + bv.y + xv.y;
    ov.z = (v.z-mean)*rs*wv.z + bv.z + xv.z;
    ov.w = (v.w-mean)*rs*wv.w + bv.w + xv.w;
    ((float4*)(out + tok*HDIM))[lane] = ov;
}

// ---------------- GEMM: C[M x N] = A[M x K] * B[N x K]^T + bias ----------------
// MODE_XW_F16 writes gate-interleaved layout: [m][n&255][n>>8] (4 f16 per row j).
enum { MODE_F16 = 0, MODE_GELU_F16 = 1, MODE_MUL_BF16 = 2, MODE_XW_F16 = 3 };

template<int MODE>
__global__ __launch_bounds__(256) void k_gemm(
    const bf16* __restrict__ A, const bf16* __restrict__ Bm,
    const float* __restrict__ bias, void* __restrict__ Cv,
    const f16* __restrict__ gatebuf,
    int K, int lda, int ldb, int ldc, int ldg)
{
    // BM=128, BN=64, BK=64; rows stored as 64 bf16 = 128B = 8x16B slots, XOR-swizzled
    __shared__ char Al[128*128];
    __shared__ char Bl[64*128];
    const int tid = threadIdx.x;
    const long bm = (long)blockIdx.x * 128;
    const int bn = blockIdx.y * 64;
    const int wave = tid >> 6, lane = tid & 63;
    const int wm = wave >> 1, wn = wave & 1;        // 2x2 waves, each 64x32
    const int l16 = lane & 15, lq = lane >> 4;
    f32x4 acc[4][2] = {};
    for (int k0 = 0; k0 < K; k0 += 64) {
        #pragma unroll
        for (int p = 0; p < 4; ++p) {               // A: 128 rows x 8 chunks
            int ci = tid + p*256;
            int row = ci >> 3, s = ci & 7;
            uint4 d = *(const uint4*)(A + (bm + row)*lda + k0 + s*8);
            *(uint4*)(Al + row*128 + ((s ^ (row&7))<<4)) = d;
        }
        #pragma unroll
        for (int p = 0; p < 2; ++p) {               // B: 64 rows x 8 chunks
            int ci = tid + p*256;
            int row = ci >> 3, s = ci & 7;
            uint4 d = *(const uint4*)(Bm + (long)(bn + row)*ldb + k0 + s*8);
            *(uint4*)(Bl + row*128 + ((s ^ (row&7))<<4)) = d;
        }
        __syncthreads();
        #pragma unroll
        for (int kc = 0; kc < 2; ++kc) {
            bf16x8 bf[2];
            #pragma unroll
            for (int fn = 0; fn < 2; ++fn) {
                int row = wn*32 + fn*16 + l16;
                int slot = (kc<<2) + lq;
                bf[fn] = *(const bf16x8*)(Bl + row*128 + ((slot ^ (row&7))<<4));
            }
            #pragma unroll
            for (int fm = 0; fm < 4; ++fm) {
                int row = wm*64 + fm*16 + l16;
                int slot = (kc<<2) + lq;
                bf16x8 af = *(const bf16x8*)(Al + row*128 + ((slot ^ (row&7))<<4));
                acc[fm][0] = __builtin_amdgcn_mfma_f32_16x16x32_bf16(af, bf[0], acc[fm][0], 0,0,0);
                acc[fm][1] = __builtin_amdgcn_mfma_f32_16x16x32_bf16(af, bf[1], acc[fm][1], 0,0,0);
            }
        }
        __syncthreads();
    }
    #pragma unroll
    for (int fm = 0; fm < 4; ++fm) {
        #pragma unroll
        for (int fn = 0; fn < 2; ++fn) {
            int n = bn + wn*32 + fn*16 + l16;
            float bv = bias[n];
            #pragma unroll
            for (int r = 0; r < 4; ++r) {
                long m = bm + wm*64 + fm*16 + lq*4 + r;
                float v = acc[fm][fn][r] + bv;
                if constexpr (MODE == MODE_F16) {
                    ((f16*)Cv)[m*ldc + n] = (f16)v;
                } else if constexpr (MODE == MODE_XW_F16) {
                    ((f16*)Cv)[m*ldc + ((n & 255) << 2) + (n >> 8)] = (f16)v;
                } else if constexpr (MODE == MODE_GELU_F16) {
                    ((f16*)Cv)[m*ldc + n] = (f16)gelu_tanh(v);
                } else {
                    float g = (float)gatebuf[m*ldg + n];
                    ((bf16*)Cv)[m*ldc + n] = __float2bfloat16(g * v);
                }
            }
        }
    }
}

// ---------------- sLSTM scan: 64 blocks (1 batch each), 1024 threads / 16 waves ----
// FINAL (revert to measured-best R9 configuration, scan = 1863us):
// MFMA i8, 4 waves/SIMD. Wave w owns j-block [w*16, w*16+16): 4 gate-tiles x
// 4 k-mfma = 16 mfma/wave/step = 256 mfma/CU/step — the MINIMUM mfma count for
// a 1024x256 GEMV at 16x16x64 (matrix-pipe floor ~1030 cyc/step on active CUs).
// B-frags (R8) register/AGPR-resident; A-frags = 4 broadcast ds_read_b128 of the
// 256B h ping-pong buffer. Raw s_barrier + lgkmcnt(0) per step (no vmcnt drain);
// x pre-acts software-pipelined 2 steps ahead in named regs XA/XB.
// Measured-neutral-or-worse and therefore excluded: chain-split (R11 +42us),
// zero-seeded accs / single fence (R12 +10us), setprio (R10), role-split (R10).

__global__ __launch_bounds__(1024) __attribute__((amdgpu_waves_per_eu(4, 4)))
void k_scan(const f16* __restrict__ xW, const char* __restrict__ R8,
            const float* __restrict__ rscale, bf16* __restrict__ h_out)
{
    __shared__ char hq[2][256];                      // i8 h, ping-pong
    const int tid = threadIdx.x;
    const int b    = blockIdx.x;
    const int w    = tid >> 6;                       // wave 0..15
    const int lane = tid & 63;
    const int c    = lane & 15;                      // j-column / gate-column
    const int q    = lane >> 4;                      // k lane-group (0..3)
    const int j    = w*16 + c;

    // ---- one-time: B-fragments (R8) -> 16 uint4 (AGPR-friendly) ----
    uint4 Bf[4][4];
    #pragma unroll
    for (int m = 0; m < 4; ++m) {
        #pragma unroll
        for (int kk = 0; kk < 4; ++kk)
            Bf[m][kk] = *(const uint4*)(R8 + (long)(j + 256*m)*256 + kk*64 + q*16);
    }
    float rs[4];
    #pragma unroll
    for (int m = 0; m < 4; ++m)
        rs[m] = rscale[j + 256*m] * (1.0f/127.0f);
    if (tid < 64) ((unsigned*)hq[0])[tid] = 0u;

    // gate-interleaved x rows; per-lane 8B for its j (4 q-replicas, broadcast).
    const char* xg = (const char*)xW + (long)b * TT * 2048 + j*8;
    bf16* hrow = h_out + (long)b * TT * HDIM;

    uint2 XA = *(const uint2*)(xg);                  // t=0
    uint2 XB = *(const uint2*)(xg + 2048);           // t=1
    float cst = 0.f, nst = 0.f, mst = 0.f;
    int cur = 0;
    __syncthreads();

#define SCAN_STEP(XREG, TPRE)                                                   \
    do {                                                                        \
        f16x2 xlo = __builtin_bit_cast(f16x2, XREG.x);                          \
        f16x2 xhi = __builtin_bit_cast(f16x2, XREG.y);                          \
        XREG = *(const uint2*)(xg + (long)(TPRE)*2048);                         \
        i32x4 af[4];                                                            \
        _Pragma("unroll")                                                       \
        for (int kk = 0; kk < 4; ++kk)                                          \
            af[kk] = __builtin_bit_cast(i32x4,                                  \
                         *(const uint4*)(hq[cur] + kk*64 + q*16));              \
        i32x4 ac0 = {0,0,0,0}, ac1 = {0,0,0,0}, ac2 = {0,0,0,0}, ac3 = {0,0,0,0}; \
        _Pragma("unroll")                                                       \
        for (int kk = 0; kk < 4; ++kk) {                                        \
            ac0 = __builtin_amdgcn_mfma_i32_16x16x64_i8(af[kk], __builtin_bit_cast(i32x4, Bf[0][kk]), ac0, 0,0,0); \
            ac1 = __builtin_amdgcn_mfma_i32_16x16x64_i8(af[kk], __builtin_bit_cast(i32x4, Bf[1][kk]), ac1, 0,0,0); \
            ac2 = __builtin_amdgcn_mfma_i32_16x16x64_i8(af[kk], __builtin_bit_cast(i32x4, Bf[2][kk]), ac2, 0,0,0); \
            ac3 = __builtin_amdgcn_mfma_i32_16x16x64_i8(af[kk], __builtin_bit_cast(i32x4, Bf[3][kk]), ac3, 0,0,0); \
        }                                                                       \
        float pz = rs[0]*(float)ac0[0] + (float)xlo[0];                         \
        float pi = rs[1]*(float)ac1[0] + (float)xlo[1];                         \
        float pf = rs[2]*(float)ac2[0] + (float)xhi[0];                         \
        float po = rs[3]*(float)ac3[0] + (float)xhi[1];                         \
        float e = __expf(-2.0f * fabsf(pz));                                    \
        float z = copysignf((1.0f - e) / (1.0f + e), pz);                       \
        float o = 1.0f / (1.0f + __expf(-po));                                  \
        float mn = fmaxf(pf + mst, pi);                                         \
        float ig = __expf(pi - mn);                                             \
        float fg = __expf(pf + mst - mn);                                       \
        cst = fg*cst + ig*z;                                                    \
        nst = fg*nst + ig;                                                      \
        mst = mn;                                                               \
        float h = o * (cst / nst);                                              \
        if (q == 0) {                                                           \
            hq[cur^1][j] = (char)(int)rintf(h * 127.f);                         \
            hrow[j] = __float2bfloat16(h);                                      \
        }                                                                       \
        __builtin_amdgcn_sched_barrier(0);                                      \
        asm volatile("s_waitcnt lgkmcnt(0)" ::: "memory");                      \
        __builtin_amdgcn_s_barrier();                                           \
        __builtin_amdgcn_sched_barrier(0);                                      \
        cur ^= 1;                                                               \
        hrow += HDIM;                                                           \
    } while (0)

    for (int t = 0; t < TT; t += 2) {
        SCAN_STEP(XA, t + 2);
        SCAN_STEP(XB, t + 3);
    }
#undef SCAN_STEP
}

// ---------------- launch ----------------
extern "C" void kernel_launch(void* const* d_in, const int* in_sizes, int n_in,
                              void* d_out, int out_size, void* d_ws, size_t ws_size,
                              hipStream_t stream) {
    const float* x     = (const float*)d_in[0];
    const float* ln1w  = (const float*)d_in[1];
    const float* ln1b  = (const float*)d_in[2];
    const float* W     = (const float*)d_in[3];
    const float* R     = (const float*)d_in[4];
    const float* bg    = (const float*)d_in[5];
    const float* upW   = (const float*)d_in[6];
    const float* upb   = (const float*)d_in[7];
    const float* gateW = (const float*)d_in[8];
    const float* gateb = (const float*)d_in[9];
    const float* downW = (const float*)d_in[10];
    const float* downb = (const float*)d_in[11];
    const float* ln2w  = (const float*)d_in[12];
    const float* ln2b  = (const float*)d_in[13];

    char* ws = (char*)d_ws;
    size_t off = 0;
    auto alloc = [&](size_t bytes) { char* p = ws + off; off += (bytes + 255) & ~255ULL; return p; };
    f16*  mlp16   = (f16*)alloc((size_t)NTOK*HDIM*2);     // holds nx first, then mlp (disjoint lifetimes)
    char* regionB = alloc((size_t)NTOK*G4*2);             // xW, then gate_out+prod
    bf16* h       = (bf16*)alloc((size_t)NTOK*HDIM*2);
    bf16* Wb      = (bf16*)alloc(262144*2);
    char* R8      = (char*)alloc(262144);
    float* rscale = (float*)alloc(1024*4);
    bf16* gWb     = (bf16*)alloc((size_t)MPAD*256*2);
    bf16* uWb     = (bf16*)alloc((size_t)MPAD*256*2);
    bf16* dWb     = (bf16*)alloc((size_t)256*MPAD*2);
    float* gbp    = (float*)alloc(MPAD*4);
    float* ubp    = (float*)alloc(MPAD*4);

    bf16* nx       = (bf16*)mlp16;                        // phase 1 use of that region
    f16*  xWb      = (f16*)regionB;                       // 131072 x 1024 f16 (gate-interleaved)
    f16*  gate_out = (f16*)regionB;                       // reuse after scan: 131072 x 384 f16
    bf16* prod     = (bf16*)(regionB + (size_t)NTOK*MPAD*2);

    k_prep_w   <<<1024, 256, 0, stream>>>(W, Wb);
    k_prep_r8  <<<256, 256, 0, stream>>>(R, R8, rscale);
    k_prep_gu  <<<384, 256, 0, stream>>>(gateW, upW, gateb, upb, gWb, uWb, gbp, ubp);
    k_prep_down<<<384, 256, 0, stream>>>(downW, dWb);
    k_ln1      <<<NTOK/4, 256, 0, stream>>>(x, ln1w, ln1b, nx);
    // xW = nx @ W^T + b   (f16, gate-interleaved per token)
    k_gemm<MODE_XW_F16><<<dim3(1024, 16), 256, 0, stream>>>(nx, Wb, bg, xWb, nullptr, 256, 256, 256, 1024, 0);
    // sequential sLSTM scan (MFMA i8, 16 waves)
    k_scan     <<<64, 1024, 0, stream>>>(xWb, R8, rscale, h);
    // gate = gelu(h @ gateW^T + gate_b)  (f16)
    k_gemm<MODE_GELU_F16><<<dim3(1024, 6), 256, 0, stream>>>(h, gWb, gbp, gate_out, nullptr, 256, 256, 256, MPAD, 0);
    // prod = gate * (h @ upW^T + up_b)   (bf16, padded cols auto-zero)
    k_gemm<MODE_MUL_BF16><<<dim3(1024, 6), 256, 0, stream>>>(h, uWb, ubp, prod, gate_out, 256, 256, 256, MPAD, MPAD);
    // mlp = prod @ downW^T + down_b      (f16 out, K=384)
    k_gemm<MODE_F16><<<dim3(1024, 4), 256, 0, stream>>>(prod, dWb, downb, mlp16, nullptr, MPAD, MPAD, MPAD, HDIM, 0);
    // out = LN(mlp) + x
    k_ln2      <<<NTOK/4, 256, 0, stream>>>(mlp16, x, ln2w, ln2b, (float*)d_out);
}